// Round 6
// baseline (12173.837 us; speedup 1.0000x reference)
//
#include <hip/hip_runtime.h>
#include <stdint.h>
#include <stddef.h>

#define T_STEPS 1024
#define BATCH   512
#define HID     256
#define DIN     64

typedef __attribute__((ext_vector_type(8))) short short8;
typedef __attribute__((ext_vector_type(4))) short short4v;
typedef __attribute__((ext_vector_type(4))) float float4v;

static __device__ __forceinline__ short f2bf(float f) {
  union { float f; unsigned u; } v; v.f = f;
  unsigned r = (v.u + 0x7FFFu + ((v.u >> 16) & 1u)) >> 16;
  return (short)r;
}
static __device__ __forceinline__ float sigm(float x) {
  return 1.0f / (1.0f + __expf(-x));
}
static __device__ __forceinline__ float tanh_f(float x) {
  return 2.0f / (1.0f + __expf(-2.0f * x)) - 1.0f;
}

// ---------------------------------------------------------------------------
// Persistent LSTM recurrence, SINGLE-BLOCK-PER-BATCH-GROUP (this round).
// 32 blocks x 1024 threads (16 waves). Each block owns 16 batch rows and the
// FULL hidden state + FULL weight set -> the h(t) dependency never leaves the
// block. The R0..R5 cross-block exchange (MALL atomics, ~7Kcy/step wall) is
// replaced by an LDS write + ONE __syncthreads per step.
//
// Register budget: per-thread weights are IDENTICAL to the 512-thread kernel
// (40 short8 fragments); the block has 2x threads so it holds 2x weights.
// 16 waves = 4 waves/SIMD -> VGPR cap 512/thread, no spill expected.
//
// Gate-major mapping (R4-verified, half -> full): wave w, lane l16 owns
// hidden unit hh = w*16+l16 (0..255); its 4 acc tiles are the 4 gates
// (cols g*256 + hh). After the K-sweep each thread holds i,f,g,o preacts
// for (rows quad*4+r, its hh) in registers; cell update is register-only.
//
// A-LDS ping-pong: step t reads buf[t&1] (h(t-1), x(t)), writes h(t) and
// x(t+1) into buf[1-(t&1)]; one barrier per step orders everything.
// No spin loops anywhere -> no hang path, fully deterministic.
// ---------------------------------------------------------------------------
__global__ __launch_bounds__(1024, 4) void lstm_kernel(
    const float* __restrict__ x, const float* __restrict__ h0,
    const float* __restrict__ c0, const float* __restrict__ W_ih,
    const float* __restrict__ W_hh, const float* __restrict__ b_ih,
    const float* __restrict__ b_hh, uint16_t* __restrict__ hs) {
  const int tid  = threadIdx.x;
  const int blk  = blockIdx.x;
  const int b0   = blk * 16;
  const int w    = tid >> 6;         // wave 0..15
  const int lane = tid & 63;
  const int quad = lane >> 4;
  const int l16  = lane & 15;
  const int w16l = w * 16 + l16;     // hidden unit hh, 0..255
  const int urow = tid >> 6;         // staging row (= wave)

  __shared__ short Alds[2][16 * 328];   // [h(256) | x(64)] bf16, ping-pong

  // ---- resident weights, gate-major: bw[j][g] is the B-fragment of
  // K-tile j (0..7 = h K-tiles, 8..9 = x K-tiles) for gate g of unit w16l.
  short8 bw[10][4];
#pragma unroll
  for (int j = 0; j < 10; ++j) {
#pragma unroll
    for (int g = 0; g < 4; ++g) {
      int grow = g * 256 + w16l;                   // output row in 4H
      const float* src = (j < 8)
          ? (W_hh + (size_t)grow * 256 + j * 32 + quad * 8)
          : (W_ih + (size_t)grow * 64 + (j - 8) * 32 + quad * 8);
      short8 bv;
#pragma unroll
      for (int e = 0; e < 8; ++e) bv[e] = f2bf(src[e]);
      bw[j][g] = bv;
    }
  }

  float bias_g[4];
#pragma unroll
  for (int g = 0; g < 4; ++g)
    bias_g[g] = b_ih[g * 256 + w16l] + b_hh[g * 256 + w16l];
  float c_reg[4];
#pragma unroll
  for (int r = 0; r < 4; ++r)
    c_reg[r] = c0[(size_t)(b0 + quad * 4 + r) * 256 + w16l];

  // ---- init buf0: h0 (16x256) + x(0) (16x64)
  {
    const float* hp = h0 + (size_t)(b0 + urow) * 256 + lane * 4;
    short4v hv4;
#pragma unroll
    for (int e = 0; e < 4; ++e) hv4[e] = f2bf(hp[e]);
    *(short4v*)&Alds[0][urow * 328 + lane * 4] = hv4;
    float xv = x[((size_t)(b0 + urow) * T_STEPS + 0) * DIN + lane];
    Alds[0][urow * 328 + 256 + lane] = f2bf(xv);
  }
  __syncthreads();

  for (int t = 0; t < T_STEPS; ++t) {
    short* RD = Alds[t & 1];          // h(t-1), x(t)
    short* WR = Alds[1 - (t & 1)];    // receives h(t), x(t+1)

    // deferred hs store: h(t-1) row-major from RD (coalesced 512B/wave),
    // fire-and-forget global write.
    if (t > 0) {
      short4v hv = *(const short4v*)&RD[urow * 328 + lane * 4];
      *(short4v*)(hs + ((size_t)(b0 + urow) * T_STEPS + (t - 1)) * HID + lane * 4) = hv;
    }
    // x(t+1) global load issued early (consumed at the end of the step)
    int tn = (t + 1 < T_STEPS) ? (t + 1) : t;
    float xf = x[((size_t)(b0 + urow) * T_STEPS + tn) * DIN + lane];

    // ---- full K-sweep: 8 h K-tiles + 2 x K-tiles, 4 gate-tiles each
    float4v acc[4] = {{0.f,0.f,0.f,0.f},{0.f,0.f,0.f,0.f},
                      {0.f,0.f,0.f,0.f},{0.f,0.f,0.f,0.f}};
#pragma unroll
    for (int j = 0; j < 8; ++j) {
      short8 a = *(const short8*)&RD[l16 * 328 + j * 32 + quad * 8];
#pragma unroll
      for (int g = 0; g < 4; ++g)
        acc[g] = __builtin_amdgcn_mfma_f32_16x16x32_bf16(a, bw[j][g], acc[g], 0, 0, 0);
    }
#pragma unroll
    for (int j = 8; j < 10; ++j) {
      short8 a = *(const short8*)&RD[l16 * 328 + 256 + (j - 8) * 32 + quad * 8];
#pragma unroll
      for (int g = 0; g < 4; ++g)
        acc[g] = __builtin_amdgcn_mfma_f32_16x16x32_bf16(a, bw[j][g], acc[g], 0, 0, 0);
    }

    // ---- cell update: all 4 gate preacts for (rows quad*4+r, hh w16l)
    // are in registers; fp32 c state in regs.
    short hb[4];
#pragma unroll
    for (int r = 0; r < 4; ++r) {
      float iv = sigm(acc[0][r] + bias_g[0]);
      float fv = sigm(acc[1][r] + bias_g[1]);
      float gv = tanh_f(acc[2][r] + bias_g[2]);
      float ov = sigm(acc[3][r] + bias_g[3]);
      float cv = fv * c_reg[r] + iv * gv;
      c_reg[r] = cv;
      hb[r] = f2bf(ov * tanh_f(cv));
    }
    // h(t) column write into WR (safe: WR's h region holds h(t-2), fully
    // consumed in step t-1; barrier at end of t-1 ordered it).
#pragma unroll
    for (int r = 0; r < 4; ++r)
      WR[(quad * 4 + r) * 328 + w16l] = hb[r];
    // x(t+1) into WR
    WR[urow * 328 + 256 + lane] = f2bf(xf);

    __syncthreads();   // h(t) + x(t+1) ready; all RD reads of this step done
  }

  // ---- epilogue: h(T-1) lives in buf[T_STEPS & 1] = buf[0]
  {
    short4v hv = *(const short4v*)&Alds[T_STEPS & 1][urow * 328 + lane * 4];
    *(short4v*)(hs + ((size_t)(b0 + urow) * T_STEPS + (T_STEPS - 1)) * HID + lane * 4) = hv;
  }
}

// ---------------------------------------------------------------------------
// One-time fp32 -> bf16 conversion of MLP weights into workspace.
// ---------------------------------------------------------------------------
__global__ void prep_kernel(const float* __restrict__ W1, const float* __restrict__ W2,
                            short* __restrict__ W1b, short* __restrict__ W2b) {
  int i = blockIdx.x * 512 + threadIdx.x;   // 160*512 = 81920 = 65536 + 16384
  if (i < 65536) W1b[i] = f2bf(W1[i]);
  else           W2b[i - 65536] = f2bf(W2[i - 65536]);
}

// ---------------------------------------------------------------------------
// Fused MLP head: y = relu(hs @ W1^T + b1) @ W2^T + b2, * mask.
// 4096 blocks x 128 rows (unchanged).
// ---------------------------------------------------------------------------
__global__ __launch_bounds__(512, 2) void mlp_kernel(
    const uint16_t* __restrict__ hs, const short* __restrict__ W1b,
    const float* __restrict__ b1, const short* __restrict__ W2b,
    const float* __restrict__ b2, const float* __restrict__ mask,
    float* __restrict__ y) {
  const int tid   = threadIdx.x;
  const int rows0 = blockIdx.x * 128;
  const int w     = tid >> 6;
  const int lane  = tid & 63;
  const int quad  = lane >> 4;
  const int l16   = lane & 15;

  __shared__ short S[128 * 264];  // h tile, later aliased as act tile

  // stage h tile [128,256] bf16
#pragma unroll
  for (int kk = 0; kk < 8; ++kk) {
    int c   = tid + kk * 512;
    int row = c >> 5;
    int off = (c & 31) * 8;
    *(short8*)&S[row * 264 + off] =
        *(const short8*)(hs + (size_t)(rows0 + row) * HID + off);
  }

  // W1 B-fragments; wave w owns hidden cols [w*32, w*32+32)
  short8 bf1[2][8];
  float  b1v[2];
#pragma unroll
  for (int nt = 0; nt < 2; ++nt) {
    int n = w * 32 + nt * 16 + l16;
    b1v[nt] = b1[n];
#pragma unroll
    for (int kt = 0; kt < 8; ++kt)
      bf1[nt][kt] = *(const short8*)(W1b + (size_t)n * 256 + kt * 32 + quad * 8);
  }
  __syncthreads();

  // GEMM1: act = relu(h @ W1^T + b1), 8 M-tiles
  float4v acc1[2][8];
#pragma unroll
  for (int nt = 0; nt < 2; ++nt)
#pragma unroll
    for (int mt = 0; mt < 8; ++mt) acc1[nt][mt] = (float4v){0.f,0.f,0.f,0.f};
#pragma unroll
  for (int kt = 0; kt < 8; ++kt) {
#pragma unroll
    for (int mt = 0; mt < 8; ++mt) {
      short8 a = *(const short8*)&S[(mt * 16 + l16) * 264 + kt * 32 + quad * 8];
#pragma unroll
      for (int nt = 0; nt < 2; ++nt)
        acc1[nt][mt] = __builtin_amdgcn_mfma_f32_16x16x32_bf16(a, bf1[nt][kt], acc1[nt][mt], 0, 0, 0);
    }
  }
  __syncthreads();  // all h reads done before aliasing S as act

#pragma unroll
  for (int nt = 0; nt < 2; ++nt) {
    int col = w * 32 + nt * 16 + l16;
#pragma unroll
    for (int mt = 0; mt < 8; ++mt)
#pragma unroll
      for (int r = 0; r < 4; ++r) {
        float v = acc1[nt][mt][r] + b1v[nt];
        v = v > 0.f ? v : 0.f;
        S[(mt * 16 + quad * 4 + r) * 264 + col] = f2bf(v);
      }
  }
  __syncthreads();

  // GEMM2: D = W2 * act^T ; wave w: out-ch tile mt2=w>>1, row half (w&1)
  const int mt2 = w >> 1;
  short8 a2[8];
#pragma unroll
  for (int kt = 0; kt < 8; ++kt)
    a2[kt] = *(const short8*)(W2b + (size_t)(mt2 * 16 + l16) * 256 + kt * 32 + quad * 8);
  float4v acc2[4] = {{0.f,0.f,0.f,0.f},{0.f,0.f,0.f,0.f},
                     {0.f,0.f,0.f,0.f},{0.f,0.f,0.f,0.f}};
#pragma unroll
  for (int kt = 0; kt < 8; ++kt) {
#pragma unroll
    for (int nt2 = 0; nt2 < 4; ++nt2) {
      int n0 = (w & 1) * 64 + nt2 * 16;
      short8 b = *(const short8*)&S[(n0 + l16) * 264 + kt * 32 + quad * 8];
      acc2[nt2] = __builtin_amdgcn_mfma_f32_16x16x32_bf16(a2[kt], b, acc2[nt2], 0, 0, 0);
    }
  }
  const float* b2p = b2 + mt2 * 16 + quad * 4;
  float b2v0 = b2p[0], b2v1 = b2p[1], b2v2 = b2p[2], b2v3 = b2p[3];
#pragma unroll
  for (int nt2 = 0; nt2 < 4; ++nt2) {
    int R = rows0 + (w & 1) * 64 + nt2 * 16 + l16;
    float m = mask[R];
    float4v out;
    out[0] = (acc2[nt2][0] + b2v0) * m;
    out[1] = (acc2[nt2][1] + b2v1) * m;
    out[2] = (acc2[nt2][2] + b2v2) * m;
    out[3] = (acc2[nt2][3] + b2v3) * m;
    *(float4v*)(y + (size_t)R * 64 + mt2 * 16 + quad * 4) = out;
  }
}

extern "C" void kernel_launch(void* const* d_in, const int* in_sizes, int n_in,
                              void* d_out, int out_size, void* d_ws, size_t ws_size,
                              hipStream_t stream) {
  (void)in_sizes; (void)n_in; (void)out_size; (void)ws_size;
  const float* x    = (const float*)d_in[0];
  const float* mask = (const float*)d_in[1];
  const float* h0   = (const float*)d_in[2];
  const float* c0   = (const float*)d_in[3];
  const float* W_ih = (const float*)d_in[4];
  const float* W_hh = (const float*)d_in[5];
  const float* b_ih = (const float*)d_in[6];
  const float* b_hh = (const float*)d_in[7];
  const float* W1   = (const float*)d_in[8];
  const float* b1   = (const float*)d_in[9];
  const float* W2   = (const float*)d_in[10];
  const float* b2   = (const float*)d_in[11];
  float* y = (float*)d_out;

  char* ws = (char*)d_ws;
  short*    W1b = (short*)ws;                            // 128 KiB
  short*    W2b = (short*)(ws + 131072);                 // 32 KiB
  uint16_t* hs  = (uint16_t*)(ws + (1u << 20));          // [B,T,H] bf16 = 256 MiB

  prep_kernel<<<160, 512, 0, stream>>>(W1, W2, W1b, W2b);
  lstm_kernel<<<32, 1024, 0, stream>>>(x, h0, c0, W_ih, W_hh, b_ih, b_hh, hs);
  mlp_kernel<<<4096, 512, 0, stream>>>(hs, W1b, b1, W2b, b2, mask, y);
}